// Round 6
// baseline (9750.657 us; speedup 1.0000x reference)
//
#include <hip/hip_runtime.h>
#include <math.h>

#define N_PTS 16384
#define M_CTR 4096
#define NS 16
#define CIN 64
#define COUT 128
#define CFEAT 67
#define CPB 4          // centers per block in passA
#define NCELL 512      // 8x8x8 grid

// order-preserving float<->uint transform (for atomic min/max on floats)
__device__ __forceinline__ unsigned ordu(float f) {
    unsigned b = __float_as_uint(f);
    return (b & 0x80000000u) ? ~b : (b | 0x80000000u);
}
__device__ __forceinline__ float unord(unsigned u) {
    unsigned b = (u & 0x80000000u) ? (u & 0x7FFFFFFFu) : ~u;
    return __uint_as_float(b);
}
__device__ __forceinline__ unsigned long long ullmax2(unsigned long long a, unsigned long long b) {
    return b > a ? b : a;
}

// ---------------- init: counters, bbox atoms, dist ----------------
__global__ void init_kernel(float* __restrict__ dist, unsigned* __restrict__ bmin,
                            unsigned* __restrict__ bmax, int* __restrict__ cnt,
                            int* __restrict__ fill)
{
    int i = blockIdx.x * blockDim.x + threadIdx.x;
    if (i < N_PTS) dist[i] = 1e10f;
    if (i < NCELL * 3) { bmin[i] = 0xFFFFFFFFu; bmax[i] = 0u; }
    if (i < NCELL) { cnt[i] = 0; fill[i] = 0; }
}

// ---------------- cloud bbox (single block, deterministic) ----------------
__global__ __launch_bounds__(256) void bbox_kernel(const float* __restrict__ p,
                                                   float* __restrict__ gbb)
{
    int t = threadIdx.x, lane = t & 63, w = t >> 6;
    float mnx = 1e30f, mny = 1e30f, mnz = 1e30f;
    float mxx = -1e30f, mxy = -1e30f, mxz = -1e30f;
    for (int i = t; i < N_PTS; i += 256) {
        float x = p[i*3], y = p[i*3+1], z = p[i*3+2];
        mnx = fminf(mnx, x); mny = fminf(mny, y); mnz = fminf(mnz, z);
        mxx = fmaxf(mxx, x); mxy = fmaxf(mxy, y); mxz = fmaxf(mxz, z);
    }
    for (int m = 1; m < 64; m <<= 1) {
        mnx = fminf(mnx, __shfl_xor(mnx, m)); mny = fminf(mny, __shfl_xor(mny, m));
        mnz = fminf(mnz, __shfl_xor(mnz, m));
        mxx = fmaxf(mxx, __shfl_xor(mxx, m)); mxy = fmaxf(mxy, __shfl_xor(mxy, m));
        mxz = fmaxf(mxz, __shfl_xor(mxz, m));
    }
    __shared__ float s[4][6];
    if (lane == 0) { s[w][0]=mnx; s[w][1]=mny; s[w][2]=mnz; s[w][3]=mxx; s[w][4]=mxy; s[w][5]=mxz; }
    __syncthreads();
    if (t == 0) {
        float a0 = fminf(fminf(s[0][0], s[1][0]), fminf(s[2][0], s[3][0]));
        float a1 = fminf(fminf(s[0][1], s[1][1]), fminf(s[2][1], s[3][1]));
        float a2 = fminf(fminf(s[0][2], s[1][2]), fminf(s[2][2], s[3][2]));
        float a3 = fmaxf(fmaxf(s[0][3], s[1][3]), fmaxf(s[2][3], s[3][3]));
        float a4 = fmaxf(fmaxf(s[0][4], s[1][4]), fmaxf(s[2][4], s[3][4]));
        float a5 = fmaxf(fmaxf(s[0][5], s[1][5]), fmaxf(s[2][5], s[3][5]));
        gbb[0]=a0; gbb[1]=a1; gbb[2]=a2; gbb[3]=a3; gbb[4]=a4; gbb[5]=a5;
    }
}

// ---------------- assign points to cells ----------------
__global__ void assign_kernel(const float* __restrict__ p, const float* __restrict__ gbb,
                              int* __restrict__ c_of, int* __restrict__ cnt)
{
    int i = blockIdx.x * blockDim.x + threadIdx.x;
    if (i >= N_PTS) return;
    float bx = gbb[0], by = gbb[1], bz = gbb[2];
    float sx = 7.9999f / fmaxf(gbb[3] - bx, 1e-20f);
    float sy = 7.9999f / fmaxf(gbb[4] - by, 1e-20f);
    float sz = 7.9999f / fmaxf(gbb[5] - bz, 1e-20f);
    float x = p[i*3], y = p[i*3+1], z = p[i*3+2];
    int ix = min(7, max(0, (int)((x - bx) * sx)));
    int iy = min(7, max(0, (int)((y - by) * sy)));
    int iz = min(7, max(0, (int)((z - bz) * sz)));
    int c = (ix << 6) | (iy << 3) | iz;
    c_of[i] = c;
    atomicAdd(&cnt[c], 1);
}

// ---------------- exclusive prefix over 512 counts ----------------
__global__ __launch_bounds__(512) void prefix_kernel(const int* __restrict__ cnt,
                                                     int* __restrict__ start)
{
    __shared__ int a[NCELL];
    int t = threadIdx.x;
    int v = cnt[t]; a[t] = v; __syncthreads();
    for (int off = 1; off < NCELL; off <<= 1) {
        int u = (t >= off) ? a[t - off] : 0;
        __syncthreads();
        a[t] += u;
        __syncthreads();
    }
    start[t] = a[t] - v;
}

// ---------------- scatter into sorted order + per-cell tight bbox ----------------
__global__ void scatter_kernel(const float* __restrict__ p, const int* __restrict__ c_of,
                               const int* __restrict__ start, int* __restrict__ fill,
                               float4* __restrict__ sp, unsigned* __restrict__ bmin,
                               unsigned* __restrict__ bmax)
{
    int i = blockIdx.x * blockDim.x + threadIdx.x;
    if (i >= N_PTS) return;
    int c = c_of[i];
    int pos = start[c] + atomicAdd(&fill[c], 1);
    float x = p[i*3], y = p[i*3+1], z = p[i*3+2];
    sp[pos] = make_float4(x, y, z, __int_as_float(i));
    atomicMin(&bmin[c*3+0], ordu(x)); atomicMax(&bmax[c*3+0], ordu(x));
    atomicMin(&bmin[c*3+1], ordu(y)); atomicMax(&bmax[c*3+1], ordu(y));
    atomicMin(&bmin[c*3+2], ordu(z)); atomicMax(&bmax[c*3+2], ordu(z));
}

// ---------------- FPS: bucket-pruned, exact ----------------
__global__ __launch_bounds__(512) void fps_kernel(const float* __restrict__ p,
                                                  const float4* __restrict__ sp,
                                                  float* __restrict__ dist,
                                                  const int* __restrict__ g_cstart,
                                                  const int* __restrict__ g_ccnt,
                                                  const unsigned* __restrict__ g_bmin,
                                                  const unsigned* __restrict__ g_bmax,
                                                  int* __restrict__ sel)
{
    __shared__ float4 bbmn[NCELL], bbmx[NCELL];          // tight per-cell bbox
    __shared__ unsigned long long key[NCELL];            // (dist_bits<<32)|~idx
    __shared__ int cst[NCELL], ccn[NCELL];
    __shared__ int wl[832];                              // chunk worklist
    __shared__ int wlc;
    __shared__ unsigned long long skw[8];

    const int t = threadIdx.x;
    const int lane = t & 63, wave = t >> 6;

    // stage cell metadata
    {
        cst[t] = g_cstart[t]; ccn[t] = g_ccnt[t];
        bbmn[t] = make_float4(unord(g_bmin[t*3]), unord(g_bmin[t*3+1]), unord(g_bmin[t*3+2]), 0.f);
        bbmx[t] = make_float4(unord(g_bmax[t*3]), unord(g_bmax[t*3+1]), unord(g_bmax[t*3+2]), 0.f);
        key[t] = 0ull;
    }
    if (t == 0) { wlc = 0; sel[0] = 0; }
    float qx = p[0], qy = p[1], qz = p[2];
    __syncthreads();

    for (int it = 1; it < M_CTR; ++it) {
        // ---- phase 1: per-cell prune test (thread t owns cell t)
        {
            int cnt = ccn[t];
            bool active = false;
            if (cnt > 0) {
                float4 mn = bbmn[t], mx = bbmx[t];
                float ddx = fmaxf(fmaxf(__fsub_rn(mn.x, qx), __fsub_rn(qx, mx.x)), 0.f);
                float ddy = fmaxf(fmaxf(__fsub_rn(mn.y, qy), __fsub_rn(qy, mx.y)), 0.f);
                float ddz = fmaxf(fmaxf(__fsub_rn(mn.z, qz), __fsub_rn(qz, mx.z)), 0.f);
                float dmin = __fadd_rn(__fadd_rn(__fmul_rn(ddx,ddx), __fmul_rn(ddy,ddy)),
                                       __fmul_rn(ddz,ddz));
                float cm = __uint_as_float((unsigned)(key[t] >> 32));
                // skip is safe iff true d2min >= cellmax; margin 1e-5 >> 4-ulp rounding
                active = (it == 1) || (dmin < cm * 1.00001f);
            }
            if (active) {
                key[t] = 0ull;
                int st = cst[t];
                int nch = (cnt + 63) >> 6;
                int base = atomicAdd(&wlc, nch);
                for (int b = 0; b < nch; ++b) wl[base + b] = (t << 14) | (st + (b << 6));
            }
        }
        __syncthreads();
        int nwl = wlc;

        // ---- phase 2: scan active chunks (two-wide for latency overlap)
        for (int e0 = wave; e0 < nwl; e0 += 16) {
            int m0 = wl[e0]; int c0 = m0 >> 14, s0 = m0 & 16383;
            int len0 = min(64, cst[c0] + ccn[c0] - s0);
            bool a0 = lane < len0;
            float4 P0; float D0;
            if (a0) { P0 = sp[s0 + lane]; D0 = dist[s0 + lane]; }

            int e1 = e0 + 8; bool h1 = e1 < nwl;
            int c1 = 0, s1 = 0, len1 = 0; bool a1 = false;
            float4 P1; float D1;
            if (h1) {
                int m1 = wl[e1]; c1 = m1 >> 14; s1 = m1 & 16383;
                len1 = min(64, cst[c1] + ccn[c1] - s1);
                a1 = lane < len1;
                if (a1) { P1 = sp[s1 + lane]; D1 = dist[s1 + lane]; }
            }

            unsigned long long k0 = 0ull;
            if (a0) {
                float dx = __fsub_rn(P0.x, qx), dy = __fsub_rn(P0.y, qy), dz = __fsub_rn(P0.z, qz);
                float d2 = __fadd_rn(__fadd_rn(__fmul_rn(dx,dx), __fmul_rn(dy,dy)),
                                     __fmul_rn(dz,dz));
                float nd = fminf(D0, d2);
                dist[s0 + lane] = nd;
                k0 = ((unsigned long long)__float_as_uint(nd) << 32)
                   | (unsigned long long)(~(unsigned)__float_as_int(P0.w));
            }
            for (int m = 1; m < 64; m <<= 1) k0 = ullmax2(k0, __shfl_xor(k0, m));
            if (lane == 0) atomicMax(&key[c0], k0);

            if (h1) {
                unsigned long long k1 = 0ull;
                if (a1) {
                    float dx = __fsub_rn(P1.x, qx), dy = __fsub_rn(P1.y, qy), dz = __fsub_rn(P1.z, qz);
                    float d2 = __fadd_rn(__fadd_rn(__fmul_rn(dx,dx), __fmul_rn(dy,dy)),
                                         __fmul_rn(dz,dz));
                    float nd = fminf(D1, d2);
                    dist[s1 + lane] = nd;
                    k1 = ((unsigned long long)__float_as_uint(nd) << 32)
                       | (unsigned long long)(~(unsigned)__float_as_int(P1.w));
                }
                for (int m = 1; m < 64; m <<= 1) k1 = ullmax2(k1, __shfl_xor(k1, m));
                if (lane == 0) atomicMax(&key[c1], k1);
            }
        }
        __syncthreads();

        // ---- phase 3: global argmax over 512 cell keys
        unsigned long long k = key[t];
        for (int m = 1; m < 64; m <<= 1) k = ullmax2(k, __shfl_xor(k, m));
        if (lane == 0) skw[wave] = k;
        if (t == 0) wlc = 0;
        __syncthreads();
        unsigned long long b0 = skw[0], b1 = skw[1], b2 = skw[2], b3 = skw[3];
        unsigned long long b4 = skw[4], b5 = skw[5], b6 = skw[6], b7 = skw[7];
        b0 = ullmax2(b0, b1); b2 = ullmax2(b2, b3); b4 = ullmax2(b4, b5); b6 = ullmax2(b6, b7);
        b0 = ullmax2(b0, b2); b4 = ullmax2(b4, b6);
        b0 = ullmax2(b0, b4);
        int widx = (int)(~(unsigned)(b0 & 0xFFFFFFFFull));
        if (t == 0) sel[it] = widx;
        int ul = __builtin_amdgcn_readfirstlane(widx);
        qx = p[ul*3+0]; qy = p[ul*3+1]; qz = p[ul*3+2];
    }
}

// ---------------- prep: pp2, gather n_p/n_n, write n_o ----------------
__global__ void prep_kernel(const float* __restrict__ p, const float* __restrict__ nrm,
                            const int* __restrict__ sel, float* __restrict__ pp2,
                            float* __restrict__ out)
{
    int i = blockIdx.x * blockDim.x + threadIdx.x;
    if (i < N_PTS) {
        float x = p[i*3], y = p[i*3+1], z = p[i*3+2];
        pp2[i] = __fadd_rn(__fadd_rn(__fmul_rn(x,x), __fmul_rn(y,y)), __fmul_rn(z,z));
    }
    if (i < M_CTR) {
        int j = sel[i];
        out[i*3+0] = p[j*3+0]; out[i*3+1] = p[j*3+1]; out[i*3+2] = p[j*3+2];
        out[12288 + i*3+0] = nrm[j*3+0];
        out[12288 + i*3+1] = nrm[j*3+1];
        out[12288 + i*3+2] = nrm[j*3+2];
    }
    if (i == 0) out[548864] = (float)M_CTR;   // n_o
}

// ---------------- kNN: one wave per center, per-lane sorted top-16 ----------------
__global__ __launch_bounds__(256) void knn_kernel(const float* __restrict__ p,
                                                  const float* __restrict__ pp2,
                                                  const float* __restrict__ np /* n_p */,
                                                  int* __restrict__ knn)
{
    const int lane = threadIdx.x & 63;
    const int wave = threadIdx.x >> 6;
    const int c = blockIdx.x * 4 + wave;

    float cx = np[c*3], cy = np[c*3+1], cz = np[c*3+2];
    float c2 = __fadd_rn(__fadd_rn(__fmul_rn(cx,cx), __fmul_rn(cy,cy)), __fmul_rn(cz,cz));

    float hd[16]; int hi[16];
#pragma unroll
    for (int k = 0; k < 16; ++k) { hd[k] = 1e30f; hi[k] = 0x7fffffff; }

    for (int t = 0; t < N_PTS/64; ++t) {
        int j = t*64 + lane;
        float px = p[j*3+0], py = p[j*3+1], pz = p[j*3+2];
        float dot = __fadd_rn(__fadd_rn(__fmul_rn(cx,px), __fmul_rn(cy,py)),
                              __fmul_rn(cz,pz));
        float d2  = __fsub_rn(__fadd_rn(c2, pp2[j]), __fmul_rn(2.0f, dot));
        if (d2 < hd[15]) {
#pragma unroll
            for (int k = 15; k >= 1; --k) {
                bool up   = d2 < hd[k-1];
                bool here = d2 < hd[k];
                hd[k] = up ? hd[k-1] : (here ? d2 : hd[k]);
                hi[k] = up ? hi[k-1] : (here ? j  : hi[k]);
            }
            if (d2 < hd[0]) { hd[0] = d2; hi[0] = j; }
        }
    }

    for (int r = 0; r < 16; ++r) {
        float wv = hd[0]; int wi = hi[0];
#pragma unroll
        for (int m = 1; m < 64; m <<= 1) {
            float ov = __shfl_xor(wv, m);
            int   oi = __shfl_xor(wi, m);
            bool b = (ov < wv) || (ov == wv && oi < wi);
            wv = b ? ov : wv; wi = b ? oi : wi;
        }
        if (hi[0] == wi) {
            knn[c*16 + r] = wi;
#pragma unroll
            for (int k = 0; k < 15; ++k) { hd[k] = hd[k+1]; hi[k] = hi[k+1]; }
            hd[15] = 1e30f; hi[15] = 0x7fffffff;
        }
    }
}

// ---------------- pass A: feat build + GEMM + stats + ymax/ymin ----------------
__global__ __launch_bounds__(128) void passA_kernel(const float* __restrict__ p,
                                                    const float* __restrict__ xf,
                                                    const float* __restrict__ W,
                                                    const int* __restrict__ knn,
                                                    const float* __restrict__ out /* n_p */,
                                                    float* __restrict__ ymax,
                                                    float* __restrict__ ymin,
                                                    float* __restrict__ partials)
{
    __shared__ float Wt[CFEAT][COUT];
    __shared__ float ft[CPB][NS][CFEAT];
    __shared__ float bsum[CPB][COUT], bssq[CPB][COUT];

    const int t = threadIdx.x;
    const int mbase = blockIdx.x * CPB;

    for (int c = 0; c < CFEAT; ++c) Wt[c][t] = W[t*CFEAT + c];

    {
        int r = t >> 1, half = t & 1;
        int ci = r >> 4, s = r & 15;
        int m = mbase + ci;
        int nb = knn[m*NS + s];
        if (half == 0) {
            ft[ci][s][0] = __fsub_rn(p[nb*3+0], out[m*3+0]);
            ft[ci][s][1] = __fsub_rn(p[nb*3+1], out[m*3+1]);
            ft[ci][s][2] = __fsub_rn(p[nb*3+2], out[m*3+2]);
        }
        for (int c = half*32; c < half*32 + 32; ++c)
            ft[ci][s][3+c] = xf[nb*CIN + c];
    }
    __syncthreads();

    const int ci = t >> 5, l = t & 31;
    float acc[NS][4];
#pragma unroll
    for (int s = 0; s < NS; ++s) { acc[s][0]=0.f; acc[s][1]=0.f; acc[s][2]=0.f; acc[s][3]=0.f; }

    for (int c = 0; c < CFEAT; ++c) {
        float w0 = Wt[c][l], w1 = Wt[c][l+32], w2 = Wt[c][l+64], w3 = Wt[c][l+96];
#pragma unroll
        for (int s = 0; s < NS; ++s) {
            float f = ft[ci][s][c];
            acc[s][0] = fmaf(f, w0, acc[s][0]);
            acc[s][1] = fmaf(f, w1, acc[s][1]);
            acc[s][2] = fmaf(f, w2, acc[s][2]);
            acc[s][3] = fmaf(f, w3, acc[s][3]);
        }
    }

    const int m = mbase + ci;
#pragma unroll
    for (int j = 0; j < 4; ++j) {
        int o = l + 32*j;
        float s = 0.f, q = 0.f, mx = -1e30f, mn = 1e30f;
#pragma unroll
        for (int sidx = 0; sidx < NS; ++sidx) {
            float v = acc[sidx][j];
            s += v; q = fmaf(v, v, q);
            mx = fmaxf(mx, v); mn = fminf(mn, v);
        }
        bsum[ci][o] = s;
        bssq[ci][o] = q;
        ymax[m*COUT + o] = mx;
        ymin[m*COUT + o] = mn;
    }
    __syncthreads();
    if (t < COUT) {
        float s = bsum[0][t] + bsum[1][t] + bsum[2][t] + bsum[3][t];
        float q = bssq[0][t] + bssq[1][t] + bssq[2][t] + bssq[3][t];
        partials[t*1024          + blockIdx.x] = s;
        partials[(COUT + t)*1024 + blockIdx.x] = q;
    }
}

// ---------------- BN stats reduce -> scale/shift ----------------
__global__ __launch_bounds__(256) void bnstat_kernel(const float* __restrict__ partials,
                                                     const float* __restrict__ gamma,
                                                     const float* __restrict__ beta,
                                                     float* __restrict__ scaleshift)
{
    __shared__ float red[256];
    int t = threadIdx.x;
    const float4* v4 = (const float4*)(partials + t*1024);
    float s = 0.f;
    for (int i = 0; i < 256; ++i) {
        float4 v = v4[i];
        s += v.x; s += v.y; s += v.z; s += v.w;
    }
    red[t] = s;
    __syncthreads();
    if (t < COUT) {
        const float inv = 1.0f / 65536.0f;
        float mean = red[t] * inv;
        float var  = red[COUT + t] * inv - mean*mean;
        float rstd = rsqrtf(var + 1e-5f);
        float g = gamma[t] * rstd;
        scaleshift[t]        = g;
        scaleshift[COUT + t] = beta[t] - mean * g;
    }
}

// ---------------- final: BN apply + ReLU on the pooled extreme ----------------
__global__ void final_kernel(float* __restrict__ y,
                             const float* __restrict__ ymin,
                             const float* __restrict__ scaleshift)
{
    int i = blockIdx.x * blockDim.x + threadIdx.x;
    if (i >= M_CTR * COUT) return;
    int o = i & (COUT - 1);
    float a = scaleshift[o], b = scaleshift[COUT + o];
    float v = (a >= 0.f) ? y[i] : ymin[i];
    float z = fmaf(a, v, b);
    y[i] = fmaxf(z, 0.f);
}

extern "C" void kernel_launch(void* const* d_in, const int* in_sizes, int n_in,
                              void* d_out, int out_size, void* d_ws, size_t ws_size,
                              hipStream_t stream)
{
    const float* p     = (const float*)d_in[0];
    const float* nrm   = (const float*)d_in[1];
    const float* xf    = (const float*)d_in[2];
    // d_in[3] = o (unused: single batch, static sizes)
    const float* W     = (const float*)d_in[4];
    const float* gamma = (const float*)d_in[5];
    const float* beta  = (const float*)d_in[6];

    float* out = (float*)d_out;
    char* ws = (char*)d_ws;
    int*   sel        = (int*)(ws + 0);            // 16 KB
    float* pp2        = (float*)(ws + 16384);      // 64 KB
    int*   knn        = (int*)(ws + 81920);        // 256 KB (overlaid by sp during FPS)
    float* ymin       = (float*)(ws + 344064);     // 2 MB  (head overlaid by FPS scratch)
    float* partials   = (float*)(ws + 2441216);    // 1 MB
    float* scaleshift = (float*)(ws + 3489792);    // 1 KB

    // FPS scratch overlays (all consumed before their hosts are written):
    float4*   sp        = (float4*)(ws + 81920);            // 256 KB in knn region
    char*     yb        = ws + 344064;                      // ymin region
    float*    dist      = (float*)(yb + 0);                 // 64 KB
    int*      c_of      = (int*)(yb + 65536);               // 64 KB
    int*      cellcnt   = (int*)(yb + 131072);              // 2 KB
    int*      cellfill  = (int*)(yb + 133120);              // 2 KB
    int*      cellstart = (int*)(yb + 135168);              // 2 KB
    unsigned* bbmin_u   = (unsigned*)(yb + 137216);         // 6 KB
    unsigned* bbmax_u   = (unsigned*)(yb + 143360);         // 6 KB
    float*    gbb       = (float*)(yb + 149504);            // 24 B

    float* ymax = out + 24576;  // y region of d_out

    init_kernel   <<<64, 256, 0, stream>>>(dist, bbmin_u, bbmax_u, cellcnt, cellfill);
    bbox_kernel   <<<1,  256, 0, stream>>>(p, gbb);
    assign_kernel <<<64, 256, 0, stream>>>(p, gbb, c_of, cellcnt);
    prefix_kernel <<<1,  512, 0, stream>>>(cellcnt, cellstart);
    scatter_kernel<<<64, 256, 0, stream>>>(p, c_of, cellstart, cellfill, sp, bbmin_u, bbmax_u);
    fps_kernel    <<<1,  512, 0, stream>>>(p, sp, dist, cellstart, cellcnt, bbmin_u, bbmax_u, sel);
    prep_kernel   <<<64, 256, 0, stream>>>(p, nrm, sel, pp2, out);
    knn_kernel    <<<1024, 256, 0, stream>>>(p, pp2, out, knn);
    passA_kernel  <<<M_CTR/CPB, 128, 0, stream>>>(p, xf, W, knn, out, ymax, ymin, partials);
    bnstat_kernel <<<1, 256, 0, stream>>>(partials, gamma, beta, scaleshift);
    final_kernel  <<<2048, 256, 0, stream>>>(ymax, ymin, scaleshift);
}

// Round 7
// 9142.852 us; speedup vs baseline: 1.0665x; 1.0665x over previous
//
#include <hip/hip_runtime.h>
#include <math.h>

#define N_PTS 16384
#define M_CTR 4096
#define NS 16
#define CIN 64
#define COUT 128
#define CFEAT 67
#define CPB 4          // centers per block in passA
#define NCELL 512      // 8x8x8 grid
#define WLMAX 768      // max chunk entries: 512 cells + 16384/128

// order-preserving float<->uint transform (for atomic min/max on floats)
__device__ __forceinline__ unsigned ordu(float f) {
    unsigned b = __float_as_uint(f);
    return (b & 0x80000000u) ? ~b : (b | 0x80000000u);
}
__device__ __forceinline__ float unord(unsigned u) {
    unsigned b = (u & 0x80000000u) ? (u & 0x7FFFFFFFu) : ~u;
    return __uint_as_float(b);
}
__device__ __forceinline__ unsigned long long ullmax2(unsigned long long a, unsigned long long b) {
    return b > a ? b : a;
}

// DPP sweeps: accumulate toward lane 63 (row_shr 1,2,4,8 + row_bcast15/31)
#define DPP_PAIR(CTRL) do { \
    int _ov = __builtin_amdgcn_update_dpp(0xbf800000, __float_as_int(bv), CTRL, 0xF, 0xF, false); \
    int _oi = __builtin_amdgcn_update_dpp(0x7fffffff, bidx, CTRL, 0xF, 0xF, false); \
    float _f = __int_as_float(_ov); \
    bool _b = (_f > bv) || (_f == bv && _oi < bidx); \
    bv = _b ? _f : bv; bidx = _b ? _oi : bidx; \
} while (0)

#define DPP_U64(CTRL) do { \
    unsigned _lo = (unsigned)k64, _hi = (unsigned)(k64 >> 32); \
    unsigned _olo = (unsigned)__builtin_amdgcn_update_dpp(0, (int)_lo, CTRL, 0xF, 0xF, false); \
    unsigned _ohi = (unsigned)__builtin_amdgcn_update_dpp(0, (int)_hi, CTRL, 0xF, 0xF, false); \
    unsigned long long _ok = ((unsigned long long)_ohi << 32) | (unsigned long long)_olo; \
    if (_ok > k64) k64 = _ok; \
} while (0)

#define DPP_IADD(CTRL) do { \
    int _o = __builtin_amdgcn_update_dpp(0, s, CTRL, 0xF, 0xF, false); \
    s += _o; \
} while (0)

#define DPP_SWEEP(M) M(0x111); M(0x112); M(0x114); M(0x118); M(0x142); M(0x143)

// ---------------- init: counters, bbox atoms, dist ----------------
__global__ void init_kernel(float* __restrict__ dist, unsigned* __restrict__ bmin,
                            unsigned* __restrict__ bmax, int* __restrict__ cnt,
                            int* __restrict__ fill)
{
    int i = blockIdx.x * blockDim.x + threadIdx.x;
    if (i < N_PTS) dist[i] = 1e10f;
    if (i < NCELL * 3) { bmin[i] = 0xFFFFFFFFu; bmax[i] = 0u; }
    if (i < NCELL) { cnt[i] = 0; fill[i] = 0; }
}

// ---------------- cloud bbox (single block, deterministic) ----------------
__global__ __launch_bounds__(256) void bbox_kernel(const float* __restrict__ p,
                                                   float* __restrict__ gbb)
{
    int t = threadIdx.x, lane = t & 63, w = t >> 6;
    float mnx = 1e30f, mny = 1e30f, mnz = 1e30f;
    float mxx = -1e30f, mxy = -1e30f, mxz = -1e30f;
    for (int i = t; i < N_PTS; i += 256) {
        float x = p[i*3], y = p[i*3+1], z = p[i*3+2];
        mnx = fminf(mnx, x); mny = fminf(mny, y); mnz = fminf(mnz, z);
        mxx = fmaxf(mxx, x); mxy = fmaxf(mxy, y); mxz = fmaxf(mxz, z);
    }
    for (int m = 1; m < 64; m <<= 1) {
        mnx = fminf(mnx, __shfl_xor(mnx, m)); mny = fminf(mny, __shfl_xor(mny, m));
        mnz = fminf(mnz, __shfl_xor(mnz, m));
        mxx = fmaxf(mxx, __shfl_xor(mxx, m)); mxy = fmaxf(mxy, __shfl_xor(mxy, m));
        mxz = fmaxf(mxz, __shfl_xor(mxz, m));
    }
    __shared__ float s[4][6];
    if (lane == 0) { s[w][0]=mnx; s[w][1]=mny; s[w][2]=mnz; s[w][3]=mxx; s[w][4]=mxy; s[w][5]=mxz; }
    __syncthreads();
    if (t == 0) {
        gbb[0] = fminf(fminf(s[0][0], s[1][0]), fminf(s[2][0], s[3][0]));
        gbb[1] = fminf(fminf(s[0][1], s[1][1]), fminf(s[2][1], s[3][1]));
        gbb[2] = fminf(fminf(s[0][2], s[1][2]), fminf(s[2][2], s[3][2]));
        gbb[3] = fmaxf(fmaxf(s[0][3], s[1][3]), fmaxf(s[2][3], s[3][3]));
        gbb[4] = fmaxf(fmaxf(s[0][4], s[1][4]), fmaxf(s[2][4], s[3][4]));
        gbb[5] = fmaxf(fmaxf(s[0][5], s[1][5]), fmaxf(s[2][5], s[3][5]));
    }
}

// ---------------- assign points to cells ----------------
__global__ void assign_kernel(const float* __restrict__ p, const float* __restrict__ gbb,
                              int* __restrict__ c_of, int* __restrict__ cnt)
{
    int i = blockIdx.x * blockDim.x + threadIdx.x;
    if (i >= N_PTS) return;
    float bx = gbb[0], by = gbb[1], bz = gbb[2];
    float sx = 7.9999f / fmaxf(gbb[3] - bx, 1e-20f);
    float sy = 7.9999f / fmaxf(gbb[4] - by, 1e-20f);
    float sz = 7.9999f / fmaxf(gbb[5] - bz, 1e-20f);
    float x = p[i*3], y = p[i*3+1], z = p[i*3+2];
    int ix = min(7, max(0, (int)((x - bx) * sx)));
    int iy = min(7, max(0, (int)((y - by) * sy)));
    int iz = min(7, max(0, (int)((z - bz) * sz)));
    int c = (ix << 6) | (iy << 3) | iz;
    c_of[i] = c;
    atomicAdd(&cnt[c], 1);
}

// ---------------- exclusive prefix over 512 counts + packed meta ----------------
__global__ __launch_bounds__(512) void prefix_kernel(const int* __restrict__ cnt,
                                                     int* __restrict__ start,
                                                     int* __restrict__ cmeta)
{
    __shared__ int a[NCELL];
    int t = threadIdx.x;
    int v = cnt[t]; a[t] = v; __syncthreads();
    for (int off = 1; off < NCELL; off <<= 1) {
        int u = (t >= off) ? a[t - off] : 0;
        __syncthreads();
        a[t] += u;
        __syncthreads();
    }
    int st = a[t] - v;
    start[t] = st;
    cmeta[t] = (st << 15) | v;
}

// ---------------- scatter into sorted order + per-cell tight bbox ----------------
__global__ void scatter_kernel(const float* __restrict__ p, const int* __restrict__ c_of,
                               const int* __restrict__ start, int* __restrict__ fill,
                               float4* __restrict__ sp, unsigned* __restrict__ bmin,
                               unsigned* __restrict__ bmax)
{
    int i = blockIdx.x * blockDim.x + threadIdx.x;
    if (i >= N_PTS) return;
    int c = c_of[i];
    int pos = start[c] + atomicAdd(&fill[c], 1);
    float x = p[i*3], y = p[i*3+1], z = p[i*3+2];
    sp[pos] = make_float4(x, y, z, __int_as_float(i));
    atomicMin(&bmin[c*3+0], ordu(x)); atomicMax(&bmax[c*3+0], ordu(x));
    atomicMin(&bmin[c*3+1], ordu(y)); atomicMax(&bmax[c*3+1], ordu(y));
    atomicMin(&bmin[c*3+2], ordu(z)); atomicMax(&bmax[c*3+2], ordu(z));
}

// ---------------- FPS: bucket-pruned, exact, low-overhead ----------------
__global__ __launch_bounds__(512) void fps_kernel(const float* __restrict__ p,
                                                  const float4* __restrict__ sp,
                                                  float* __restrict__ dist,
                                                  const int* __restrict__ g_cmeta,
                                                  const unsigned* __restrict__ g_bmin,
                                                  const unsigned* __restrict__ g_bmax,
                                                  int* __restrict__ sel)
{
    __shared__ unsigned long long key[NCELL];   // (dist_bits<<32)|~idx, cached per cell
    __shared__ int cmeta[NCELL];                // (start<<15)|cnt
    __shared__ unsigned short wl[WLMAX];        // (cell<<7)|chunk
    __shared__ unsigned long long skw[8];
    __shared__ int wlc;

    const int t = threadIdx.x;
    const int lane = t & 63, wave = t >> 6;

    // thread t owns cell t: bbox + meta in registers (no arrays)
    const int meta_r = g_cmeta[t];
    cmeta[t] = meta_r;
    key[t] = 0ull;
    const int my_cnt = meta_r & 0x7FFF;
    const float mnx = unord(g_bmin[t*3+0]), mny = unord(g_bmin[t*3+1]), mnz = unord(g_bmin[t*3+2]);
    const float mxx = unord(g_bmax[t*3+0]), mxy = unord(g_bmax[t*3+1]), mxz = unord(g_bmax[t*3+2]);

    if (t == 0) { wlc = 0; sel[0] = 0; }
    float qx = p[0], qy = p[1], qz = p[2];   // last = 0
    __syncthreads();

    for (int it = 1; it < M_CTR; ++it) {
        // ---- phase 1: prune test (registers only) + wave-aggregated append
        int nch = 0;
        if (my_cnt > 0) {
            float ddx = fmaxf(fmaxf(__fsub_rn(mnx, qx), __fsub_rn(qx, mxx)), 0.f);
            float ddy = fmaxf(fmaxf(__fsub_rn(mny, qy), __fsub_rn(qy, mxy)), 0.f);
            float ddz = fmaxf(fmaxf(__fsub_rn(mnz, qz), __fsub_rn(qz, mxz)), 0.f);
            float dmin = __fadd_rn(__fadd_rn(__fmul_rn(ddx,ddx), __fmul_rn(ddy,ddy)),
                                   __fmul_rn(ddz,ddz));
            float cm = __uint_as_float((unsigned)(key[t] >> 32));
            // skip safe iff d2min >= cellmax; margin 1e-5 >> 5-op rounding
            if (it == 1 || dmin < cm * 1.00001f) nch = (my_cnt + 127) >> 7;
        }
        if (nch) key[t] = 0ull;   // reset before rescan (owner-only, pre-barrier)

        int s = nch;
        DPP_SWEEP(DPP_IADD);                       // lane63 = wave total
        int base = 0;
        if (lane == 63 && s > 0) base = atomicAdd(&wlc, s);
        base = __shfl(base, 63);
        int cum = 0;
        for (int k = 0; ; ++k) {
            unsigned long long mk = __ballot(nch > k);
            if (!mk) break;
            if (nch > k)
                wl[base + cum + (int)__popcll(mk & ((1ull << lane) - 1ull))] =
                    (unsigned short)((t << 7) | k);
            cum += (int)__popcll(mk);
        }
        __syncthreads();
        const int nwl = wlc;

        // ---- phase 2: scan active 128-pt chunks, DPP reduce, atomic combine
        for (int e = wave; e < nwl; e += 8) {
            int ent = wl[e];
            int c = ent >> 7, ch = ent & 127;
            int m2 = cmeta[c];
            int st = m2 >> 15, cnt = m2 & 0x7FFF;
            int b0 = ch << 7;
            float bv = -1.0f; int bidx = 0x7fffffff;
            int o0 = b0 + lane;
            if (o0 < cnt) {
                float4 P = sp[st + o0];
                float D = dist[st + o0];
                float dx = __fsub_rn(P.x, qx), dy = __fsub_rn(P.y, qy), dz = __fsub_rn(P.z, qz);
                float d2 = __fadd_rn(__fadd_rn(__fmul_rn(dx,dx), __fmul_rn(dy,dy)),
                                     __fmul_rn(dz,dz));
                float nd = fminf(D, d2);
                dist[st + o0] = nd;
                bv = nd; bidx = __float_as_int(P.w);
            }
            int o1 = o0 + 64;
            if (o1 < cnt) {
                float4 P = sp[st + o1];
                float D = dist[st + o1];
                float dx = __fsub_rn(P.x, qx), dy = __fsub_rn(P.y, qy), dz = __fsub_rn(P.z, qz);
                float d2 = __fadd_rn(__fadd_rn(__fmul_rn(dx,dx), __fmul_rn(dy,dy)),
                                     __fmul_rn(dz,dz));
                float nd = fminf(D, d2);
                dist[st + o1] = nd;
                int oi = __float_as_int(P.w);
                bool b = (nd > bv) || (nd == bv && oi < bidx);
                bv = b ? nd : bv; bidx = b ? oi : bidx;
            }
            DPP_SWEEP(DPP_PAIR);                   // lane63 = chunk (max d, min idx)
            if (lane == 63)
                atomicMax(&key[c],
                          ((unsigned long long)__float_as_uint(bv) << 32) |
                          (unsigned long long)(~(unsigned)bidx));
        }
        __syncthreads();

        // ---- phase 3: global argmax over 512 cached cell keys
        unsigned long long k64 = key[t];
        DPP_SWEEP(DPP_U64);
        if (lane == 63) skw[wave] = k64;
        if (t == 0) wlc = 0;
        __syncthreads();
        unsigned long long a0 = ullmax2(skw[0], skw[1]);
        unsigned long long a1 = ullmax2(skw[2], skw[3]);
        unsigned long long a2 = ullmax2(skw[4], skw[5]);
        unsigned long long a3 = ullmax2(skw[6], skw[7]);
        a0 = ullmax2(a0, a1); a2 = ullmax2(a2, a3);
        a0 = ullmax2(a0, a2);
        int widx = (int)(~(unsigned)(a0 & 0xFFFFFFFFull));
        if (t == 0) sel[it] = widx;
        int ul = __builtin_amdgcn_readfirstlane(widx);
        qx = p[ul*3+0]; qy = p[ul*3+1]; qz = p[ul*3+2];
    }
}

// ---------------- prep: pp2, gather n_p/n_n, write n_o ----------------
__global__ void prep_kernel(const float* __restrict__ p, const float* __restrict__ nrm,
                            const int* __restrict__ sel, float* __restrict__ pp2,
                            float* __restrict__ out)
{
    int i = blockIdx.x * blockDim.x + threadIdx.x;
    if (i < N_PTS) {
        float x = p[i*3], y = p[i*3+1], z = p[i*3+2];
        pp2[i] = __fadd_rn(__fadd_rn(__fmul_rn(x,x), __fmul_rn(y,y)), __fmul_rn(z,z));
    }
    if (i < M_CTR) {
        int j = sel[i];
        out[i*3+0] = p[j*3+0]; out[i*3+1] = p[j*3+1]; out[i*3+2] = p[j*3+2];
        out[12288 + i*3+0] = nrm[j*3+0];
        out[12288 + i*3+1] = nrm[j*3+1];
        out[12288 + i*3+2] = nrm[j*3+2];
    }
    if (i == 0) out[548864] = (float)M_CTR;   // n_o
}

// ---------------- kNN: one wave per center, per-lane sorted top-16 ----------------
__global__ __launch_bounds__(256) void knn_kernel(const float* __restrict__ p,
                                                  const float* __restrict__ pp2,
                                                  const float* __restrict__ np /* n_p */,
                                                  int* __restrict__ knn)
{
    const int lane = threadIdx.x & 63;
    const int wave = threadIdx.x >> 6;
    const int c = blockIdx.x * 4 + wave;

    float cx = np[c*3], cy = np[c*3+1], cz = np[c*3+2];
    float c2 = __fadd_rn(__fadd_rn(__fmul_rn(cx,cx), __fmul_rn(cy,cy)), __fmul_rn(cz,cz));

    float hd[16]; int hi[16];
#pragma unroll
    for (int k = 0; k < 16; ++k) { hd[k] = 1e30f; hi[k] = 0x7fffffff; }

    for (int t = 0; t < N_PTS/64; ++t) {
        int j = t*64 + lane;
        float px = p[j*3+0], py = p[j*3+1], pz = p[j*3+2];
        float dot = __fadd_rn(__fadd_rn(__fmul_rn(cx,px), __fmul_rn(cy,py)),
                              __fmul_rn(cz,pz));
        float d2  = __fsub_rn(__fadd_rn(c2, pp2[j]), __fmul_rn(2.0f, dot));
        if (d2 < hd[15]) {
#pragma unroll
            for (int k = 15; k >= 1; --k) {
                bool up   = d2 < hd[k-1];
                bool here = d2 < hd[k];
                hd[k] = up ? hd[k-1] : (here ? d2 : hd[k]);
                hi[k] = up ? hi[k-1] : (here ? j  : hi[k]);
            }
            if (d2 < hd[0]) { hd[0] = d2; hi[0] = j; }
        }
    }

    for (int r = 0; r < 16; ++r) {
        float wv = hd[0]; int wi = hi[0];
#pragma unroll
        for (int m = 1; m < 64; m <<= 1) {
            float ov = __shfl_xor(wv, m);
            int   oi = __shfl_xor(wi, m);
            bool b = (ov < wv) || (ov == wv && oi < wi);
            wv = b ? ov : wv; wi = b ? oi : wi;
        }
        if (hi[0] == wi) {
            knn[c*16 + r] = wi;
#pragma unroll
            for (int k = 0; k < 15; ++k) { hd[k] = hd[k+1]; hi[k] = hi[k+1]; }
            hd[15] = 1e30f; hi[15] = 0x7fffffff;
        }
    }
}

// ---------------- pass A: feat build + GEMM + stats + ymax/ymin ----------------
__global__ __launch_bounds__(128) void passA_kernel(const float* __restrict__ p,
                                                    const float* __restrict__ xf,
                                                    const float* __restrict__ W,
                                                    const int* __restrict__ knn,
                                                    const float* __restrict__ out /* n_p */,
                                                    float* __restrict__ ymax,
                                                    float* __restrict__ ymin,
                                                    float* __restrict__ partials)
{
    __shared__ float Wt[CFEAT][COUT];
    __shared__ float ft[CPB][NS][CFEAT];
    __shared__ float bsum[CPB][COUT], bssq[CPB][COUT];

    const int t = threadIdx.x;
    const int mbase = blockIdx.x * CPB;

    for (int c = 0; c < CFEAT; ++c) Wt[c][t] = W[t*CFEAT + c];

    {
        int r = t >> 1, half = t & 1;
        int ci = r >> 4, s = r & 15;
        int m = mbase + ci;
        int nb = knn[m*NS + s];
        if (half == 0) {
            ft[ci][s][0] = __fsub_rn(p[nb*3+0], out[m*3+0]);
            ft[ci][s][1] = __fsub_rn(p[nb*3+1], out[m*3+1]);
            ft[ci][s][2] = __fsub_rn(p[nb*3+2], out[m*3+2]);
        }
        for (int c = half*32; c < half*32 + 32; ++c)
            ft[ci][s][3+c] = xf[nb*CIN + c];
    }
    __syncthreads();

    const int ci = t >> 5, l = t & 31;
    float acc[NS][4];
#pragma unroll
    for (int s = 0; s < NS; ++s) { acc[s][0]=0.f; acc[s][1]=0.f; acc[s][2]=0.f; acc[s][3]=0.f; }

    for (int c = 0; c < CFEAT; ++c) {
        float w0 = Wt[c][l], w1 = Wt[c][l+32], w2 = Wt[c][l+64], w3 = Wt[c][l+96];
#pragma unroll
        for (int s = 0; s < NS; ++s) {
            float f = ft[ci][s][c];
            acc[s][0] = fmaf(f, w0, acc[s][0]);
            acc[s][1] = fmaf(f, w1, acc[s][1]);
            acc[s][2] = fmaf(f, w2, acc[s][2]);
            acc[s][3] = fmaf(f, w3, acc[s][3]);
        }
    }

    const int m = mbase + ci;
#pragma unroll
    for (int j = 0; j < 4; ++j) {
        int o = l + 32*j;
        float s = 0.f, q = 0.f, mx = -1e30f, mn = 1e30f;
#pragma unroll
        for (int sidx = 0; sidx < NS; ++sidx) {
            float v = acc[sidx][j];
            s += v; q = fmaf(v, v, q);
            mx = fmaxf(mx, v); mn = fminf(mn, v);
        }
        bsum[ci][o] = s;
        bssq[ci][o] = q;
        ymax[m*COUT + o] = mx;
        ymin[m*COUT + o] = mn;
    }
    __syncthreads();
    if (t < COUT) {
        float s = bsum[0][t] + bsum[1][t] + bsum[2][t] + bsum[3][t];
        float q = bssq[0][t] + bssq[1][t] + bssq[2][t] + bssq[3][t];
        partials[t*1024          + blockIdx.x] = s;
        partials[(COUT + t)*1024 + blockIdx.x] = q;
    }
}

// ---------------- BN stats reduce -> scale/shift ----------------
__global__ __launch_bounds__(256) void bnstat_kernel(const float* __restrict__ partials,
                                                     const float* __restrict__ gamma,
                                                     const float* __restrict__ beta,
                                                     float* __restrict__ scaleshift)
{
    __shared__ float red[256];
    int t = threadIdx.x;
    const float4* v4 = (const float4*)(partials + t*1024);
    float s = 0.f;
    for (int i = 0; i < 256; ++i) {
        float4 v = v4[i];
        s += v.x; s += v.y; s += v.z; s += v.w;
    }
    red[t] = s;
    __syncthreads();
    if (t < COUT) {
        const float inv = 1.0f / 65536.0f;
        float mean = red[t] * inv;
        float var  = red[COUT + t] * inv - mean*mean;
        float rstd = rsqrtf(var + 1e-5f);
        float g = gamma[t] * rstd;
        scaleshift[t]        = g;
        scaleshift[COUT + t] = beta[t] - mean * g;
    }
}

// ---------------- final: BN apply + ReLU on the pooled extreme ----------------
__global__ void final_kernel(float* __restrict__ y,
                             const float* __restrict__ ymin,
                             const float* __restrict__ scaleshift)
{
    int i = blockIdx.x * blockDim.x + threadIdx.x;
    if (i >= M_CTR * COUT) return;
    int o = i & (COUT - 1);
    float a = scaleshift[o], b = scaleshift[COUT + o];
    float v = (a >= 0.f) ? y[i] : ymin[i];
    float z = fmaf(a, v, b);
    y[i] = fmaxf(z, 0.f);
}

extern "C" void kernel_launch(void* const* d_in, const int* in_sizes, int n_in,
                              void* d_out, int out_size, void* d_ws, size_t ws_size,
                              hipStream_t stream)
{
    const float* p     = (const float*)d_in[0];
    const float* nrm   = (const float*)d_in[1];
    const float* xf    = (const float*)d_in[2];
    // d_in[3] = o (unused: single batch, static sizes)
    const float* W     = (const float*)d_in[4];
    const float* gamma = (const float*)d_in[5];
    const float* beta  = (const float*)d_in[6];

    float* out = (float*)d_out;
    char* ws = (char*)d_ws;
    int*   sel        = (int*)(ws + 0);            // 16 KB
    float* pp2        = (float*)(ws + 16384);      // 64 KB
    int*   knn        = (int*)(ws + 81920);        // 256 KB (overlaid by sp during FPS)
    float* ymin       = (float*)(ws + 344064);     // 2 MB  (head overlaid by FPS scratch)
    float* partials   = (float*)(ws + 2441216);    // 1 MB
    float* scaleshift = (float*)(ws + 3489792);    // 1 KB

    // FPS scratch overlays (all consumed before their hosts are written):
    float4*   sp        = (float4*)(ws + 81920);            // 256 KB in knn region
    char*     yb        = ws + 344064;                      // ymin region
    float*    dist      = (float*)(yb + 0);                 // 64 KB
    int*      c_of      = (int*)(yb + 65536);               // 64 KB
    int*      cellcnt   = (int*)(yb + 131072);              // 2 KB
    int*      cellfill  = (int*)(yb + 133120);              // 2 KB
    int*      cellstart = (int*)(yb + 135168);              // 2 KB
    unsigned* bbmin_u   = (unsigned*)(yb + 137216);         // 6 KB
    unsigned* bbmax_u   = (unsigned*)(yb + 143360);         // 6 KB
    float*    gbb       = (float*)(yb + 149504);            // 24 B
    int*      cmeta_g   = (int*)(yb + 149536);              // 2 KB

    float* ymax = out + 24576;  // y region of d_out

    init_kernel   <<<64, 256, 0, stream>>>(dist, bbmin_u, bbmax_u, cellcnt, cellfill);
    bbox_kernel   <<<1,  256, 0, stream>>>(p, gbb);
    assign_kernel <<<64, 256, 0, stream>>>(p, gbb, c_of, cellcnt);
    prefix_kernel <<<1,  512, 0, stream>>>(cellcnt, cellstart, cmeta_g);
    scatter_kernel<<<64, 256, 0, stream>>>(p, c_of, cellstart, cellfill, sp, bbmin_u, bbmax_u);
    fps_kernel    <<<1,  512, 0, stream>>>(p, sp, dist, cmeta_g, bbmin_u, bbmax_u, sel);
    prep_kernel   <<<64, 256, 0, stream>>>(p, nrm, sel, pp2, out);
    knn_kernel    <<<1024, 256, 0, stream>>>(p, pp2, out, knn);
    passA_kernel  <<<M_CTR/CPB, 128, 0, stream>>>(p, xf, W, knn, out, ymax, ymin, partials);
    bnstat_kernel <<<1, 256, 0, stream>>>(partials, gamma, beta, scaleshift);
    final_kernel  <<<2048, 256, 0, stream>>>(ymax, ymin, scaleshift);
}

// Round 8
// 8330.495 us; speedup vs baseline: 1.1705x; 1.0975x over previous
//
#include <hip/hip_runtime.h>
#include <math.h>

#define N_PTS 16384
#define M_CTR 4096
#define NS 16
#define CIN 64
#define COUT 128
#define CFEAT 67
#define CPB 4          // centers per block in passA
#define NCELL 512      // 8x8x8 grid
#define WLMAX 768      // max chunk entries: 512 cells + 16384/128

// order-preserving float<->uint transform (for atomic min/max on floats)
__device__ __forceinline__ unsigned ordu(float f) {
    unsigned b = __float_as_uint(f);
    return (b & 0x80000000u) ? ~b : (b | 0x80000000u);
}
__device__ __forceinline__ float unord(unsigned u) {
    unsigned b = (u & 0x80000000u) ? (u & 0x7FFFFFFFu) : ~u;
    return __uint_as_float(b);
}
__device__ __forceinline__ unsigned long long ullmax2(unsigned long long a, unsigned long long b) {
    return b > a ? b : a;
}

// DPP sweeps toward lane 63: row_shr 1,2,4,8 + row_bcast15 + row_bcast31
#define DPP_PAIR(CTRL) do { \
    int _ov = __builtin_amdgcn_update_dpp(0xbf800000, __float_as_int(bv), CTRL, 0xF, 0xF, false); \
    int _oi = __builtin_amdgcn_update_dpp(0x7fffffff, bidx, CTRL, 0xF, 0xF, false); \
    float _f = __int_as_float(_ov); \
    bool _b = (_f > bv) || (_f == bv && _oi < bidx); \
    bv = _b ? _f : bv; bidx = _b ? _oi : bidx; \
} while (0)

#define DPP_IADD(CTRL) do { \
    int _o = __builtin_amdgcn_update_dpp(0, s, CTRL, 0xF, 0xF, false); \
    s += _o; \
} while (0)

// top-2 u64 merge: each lane carries (k1 >= k2); merge with shifted pair
#define DPP_TOP2(CTRL) do { \
    unsigned _o1lo = (unsigned)__builtin_amdgcn_update_dpp(0, (int)(unsigned)k1, CTRL, 0xF, 0xF, false); \
    unsigned _o1hi = (unsigned)__builtin_amdgcn_update_dpp(0, (int)(unsigned)(k1>>32), CTRL, 0xF, 0xF, false); \
    unsigned _o2lo = (unsigned)__builtin_amdgcn_update_dpp(0, (int)(unsigned)k2, CTRL, 0xF, 0xF, false); \
    unsigned _o2hi = (unsigned)__builtin_amdgcn_update_dpp(0, (int)(unsigned)(k2>>32), CTRL, 0xF, 0xF, false); \
    unsigned long long _o1 = ((unsigned long long)_o1hi << 32) | (unsigned long long)_o1lo; \
    unsigned long long _o2 = ((unsigned long long)_o2hi << 32) | (unsigned long long)_o2lo; \
    unsigned long long _n1 = k1 > _o1 ? k1 : _o1; \
    unsigned long long _lo = k1 > _o1 ? _o1 : k1; \
    unsigned long long _m2 = k2 > _o2 ? k2 : _o2; \
    k2 = _lo > _m2 ? _lo : _m2; \
    k1 = _n1; \
} while (0)

#define DPP_SWEEP(M) M(0x111); M(0x112); M(0x114); M(0x118); M(0x142); M(0x143)

// ---------------- init: counters, bbox atoms ----------------
__global__ void init_kernel(unsigned* __restrict__ bmin, unsigned* __restrict__ bmax,
                            int* __restrict__ cnt, int* __restrict__ fill)
{
    int i = blockIdx.x * blockDim.x + threadIdx.x;
    if (i < NCELL * 3) { bmin[i] = 0xFFFFFFFFu; bmax[i] = 0u; }
    if (i < NCELL) { cnt[i] = 0; fill[i] = 0; }
}

// ---------------- cloud bbox (single block, deterministic) ----------------
__global__ __launch_bounds__(256) void bbox_kernel(const float* __restrict__ p,
                                                   float* __restrict__ gbb)
{
    int t = threadIdx.x, lane = t & 63, w = t >> 6;
    float mnx = 1e30f, mny = 1e30f, mnz = 1e30f;
    float mxx = -1e30f, mxy = -1e30f, mxz = -1e30f;
    for (int i = t; i < N_PTS; i += 256) {
        float x = p[i*3], y = p[i*3+1], z = p[i*3+2];
        mnx = fminf(mnx, x); mny = fminf(mny, y); mnz = fminf(mnz, z);
        mxx = fmaxf(mxx, x); mxy = fmaxf(mxy, y); mxz = fmaxf(mxz, z);
    }
    for (int m = 1; m < 64; m <<= 1) {
        mnx = fminf(mnx, __shfl_xor(mnx, m)); mny = fminf(mny, __shfl_xor(mny, m));
        mnz = fminf(mnz, __shfl_xor(mnz, m));
        mxx = fmaxf(mxx, __shfl_xor(mxx, m)); mxy = fmaxf(mxy, __shfl_xor(mxy, m));
        mxz = fmaxf(mxz, __shfl_xor(mxz, m));
    }
    __shared__ float s[4][6];
    if (lane == 0) { s[w][0]=mnx; s[w][1]=mny; s[w][2]=mnz; s[w][3]=mxx; s[w][4]=mxy; s[w][5]=mxz; }
    __syncthreads();
    if (t == 0) {
        gbb[0] = fminf(fminf(s[0][0], s[1][0]), fminf(s[2][0], s[3][0]));
        gbb[1] = fminf(fminf(s[0][1], s[1][1]), fminf(s[2][1], s[3][1]));
        gbb[2] = fminf(fminf(s[0][2], s[1][2]), fminf(s[2][2], s[3][2]));
        gbb[3] = fmaxf(fmaxf(s[0][3], s[1][3]), fmaxf(s[2][3], s[3][3]));
        gbb[4] = fmaxf(fmaxf(s[0][4], s[1][4]), fmaxf(s[2][4], s[3][4]));
        gbb[5] = fmaxf(fmaxf(s[0][5], s[1][5]), fmaxf(s[2][5], s[3][5]));
    }
}

// ---------------- assign points to cells ----------------
__global__ void assign_kernel(const float* __restrict__ p, const float* __restrict__ gbb,
                              int* __restrict__ c_of, int* __restrict__ cnt)
{
    int i = blockIdx.x * blockDim.x + threadIdx.x;
    if (i >= N_PTS) return;
    float bx = gbb[0], by = gbb[1], bz = gbb[2];
    float sx = 7.9999f / fmaxf(gbb[3] - bx, 1e-20f);
    float sy = 7.9999f / fmaxf(gbb[4] - by, 1e-20f);
    float sz = 7.9999f / fmaxf(gbb[5] - bz, 1e-20f);
    float x = p[i*3], y = p[i*3+1], z = p[i*3+2];
    int ix = min(7, max(0, (int)((x - bx) * sx)));
    int iy = min(7, max(0, (int)((y - by) * sy)));
    int iz = min(7, max(0, (int)((z - bz) * sz)));
    int c = (ix << 6) | (iy << 3) | iz;
    c_of[i] = c;
    atomicAdd(&cnt[c], 1);
}

// ---------------- exclusive prefix over 512 counts + packed meta ----------------
__global__ __launch_bounds__(512) void prefix_kernel(const int* __restrict__ cnt,
                                                     int* __restrict__ start,
                                                     int* __restrict__ cmeta)
{
    __shared__ int a[NCELL];
    int t = threadIdx.x;
    int v = cnt[t]; a[t] = v; __syncthreads();
    for (int off = 1; off < NCELL; off <<= 1) {
        int u = (t >= off) ? a[t - off] : 0;
        __syncthreads();
        a[t] += u;
        __syncthreads();
    }
    int st = a[t] - v;
    start[t] = st;
    cmeta[t] = (st << 15) | v;
}

// ---------------- scatter into sorted order + per-cell tight bbox ----------------
__global__ void scatter_kernel(const float* __restrict__ p, const int* __restrict__ c_of,
                               const int* __restrict__ start, int* __restrict__ fill,
                               float4* __restrict__ sp, unsigned* __restrict__ bmin,
                               unsigned* __restrict__ bmax)
{
    int i = blockIdx.x * blockDim.x + threadIdx.x;
    if (i >= N_PTS) return;
    int c = c_of[i];
    int pos = start[c] + atomicAdd(&fill[c], 1);
    float x = p[i*3], y = p[i*3+1], z = p[i*3+2];
    sp[pos] = make_float4(x, y, z, __int_as_float(i));
    atomicMin(&bmin[c*3+0], ordu(x)); atomicMax(&bmax[c*3+0], ordu(x));
    atomicMin(&bmin[c*3+1], ordu(y)); atomicMax(&bmax[c*3+1], ordu(y));
    atomicMin(&bmin[c*3+2], ordu(z)); atomicMax(&bmax[c*3+2], ordu(z));
}

// ---------------- FPS: bucket-pruned, exact, LDS-dist + top-2 batch ----------------
__global__ __launch_bounds__(512) void fps_kernel(const float* __restrict__ p,
                                                  const float4* __restrict__ sp,
                                                  const int* __restrict__ g_cmeta,
                                                  const unsigned* __restrict__ g_bmin,
                                                  const unsigned* __restrict__ g_bmax,
                                                  int* __restrict__ sel)
{
    __shared__ float distl[N_PTS];               // 64 KB
    __shared__ unsigned long long key[NCELL];    // 4 KB  (dist_bits<<32)|~idx
    __shared__ unsigned wl[WLMAX];               // 3 KB  (st<<17)|(c<<8)|len
    __shared__ unsigned long long skw1[8], skw2[8];
    __shared__ int wlc;

    const int t = threadIdx.x;
    const int lane = t & 63, wave = t >> 6;

    for (int i = t; i < N_PTS; i += 512) distl[i] = 1e10f;

    const int meta = g_cmeta[t];
    const int my_cnt = meta & 0x7FFF;
    const int my_st  = meta >> 15;
    const float mnx = unord(g_bmin[t*3+0]), mny = unord(g_bmin[t*3+1]), mnz = unord(g_bmin[t*3+2]);
    const float mxx = unord(g_bmax[t*3+0]), mxy = unord(g_bmax[t*3+1]), mxz = unord(g_bmax[t*3+2]);
    key[t] = 0ull;
    unsigned long long kreg = 0ull;   // cached key of my cell (mirror of key[t])

    if (t == 0) { wlc = 0; sel[0] = 0; }
    float q1x = p[0], q1y = p[1], q1z = p[2];
    float q2x = 0.f, q2y = 0.f, q2z = 0.f;
    bool two = false;
    bool first = true;
    __syncthreads();

    int it = 1;
    while (it < M_CTR) {
        // ---- phase 1: register-only prune + wave-aggregated worklist append
        int nch = 0;
        if (my_cnt > 0) {
            bool act;
            if (first) act = true;
            else {
                float cm = __uint_as_float((unsigned)(kreg >> 32)) * 1.00001f;
                float ddx = fmaxf(fmaxf(__fsub_rn(mnx, q1x), __fsub_rn(q1x, mxx)), 0.f);
                float ddy = fmaxf(fmaxf(__fsub_rn(mny, q1y), __fsub_rn(q1y, mxy)), 0.f);
                float ddz = fmaxf(fmaxf(__fsub_rn(mnz, q1z), __fsub_rn(q1z, mxz)), 0.f);
                float dm1 = __fadd_rn(__fadd_rn(__fmul_rn(ddx,ddx), __fmul_rn(ddy,ddy)),
                                      __fmul_rn(ddz,ddz));
                act = dm1 < cm;
                if (!act && two) {
                    float ex = fmaxf(fmaxf(__fsub_rn(mnx, q2x), __fsub_rn(q2x, mxx)), 0.f);
                    float ey = fmaxf(fmaxf(__fsub_rn(mny, q2y), __fsub_rn(q2y, mxy)), 0.f);
                    float ez = fmaxf(fmaxf(__fsub_rn(mnz, q2z), __fsub_rn(q2z, mxz)), 0.f);
                    float dm2 = __fadd_rn(__fadd_rn(__fmul_rn(ex,ex), __fmul_rn(ey,ey)),
                                          __fmul_rn(ez,ez));
                    act = dm2 < cm;
                }
            }
            if (act) nch = (my_cnt + 127) >> 7;
        }
        if (nch) key[t] = 0ull;

        int s = nch;
        DPP_SWEEP(DPP_IADD);                       // lane63 = wave total
        int base = 0;
        if (lane == 63 && s > 0) base = atomicAdd(&wlc, s);
        base = __shfl(base, 63);
        int cum = 0;
        for (int k = 0; ; ++k) {
            unsigned long long mk = __ballot(nch > k);
            if (!mk) break;
            if (nch > k) {
                int cst = my_st + (k << 7);
                int len = min(128, my_cnt - (k << 7));
                wl[base + cum + (int)__popcll(mk & ((1ull << lane) - 1ull))] =
                    ((unsigned)cst << 17) | ((unsigned)t << 8) | (unsigned)len;
            }
            cum += (int)__popcll(mk);
        }
        __syncthreads();
        const int nwl = wlc;

        // ---- phase 2: scan active chunks (dist in LDS, self-contained entries)
        for (int e = wave; e < nwl; e += 8) {
            unsigned ent = wl[e];
            int st  = (int)(ent >> 17);
            int c   = (int)((ent >> 8) & 511u);
            int len = (int)(ent & 255u);
            float bv = -1.0f; int bidx = 0x7fffffff;
            int o0 = lane;
            if (o0 < len) {
                int g = st + o0;
                float4 P = sp[g];
                float D = distl[g];
                float dx = __fsub_rn(P.x, q1x), dy = __fsub_rn(P.y, q1y), dz = __fsub_rn(P.z, q1z);
                float d2 = __fadd_rn(__fadd_rn(__fmul_rn(dx,dx), __fmul_rn(dy,dy)),
                                     __fmul_rn(dz,dz));
                float nd = fminf(D, d2);
                if (two) {
                    float ex = __fsub_rn(P.x, q2x), ey = __fsub_rn(P.y, q2y), ez = __fsub_rn(P.z, q2z);
                    float e2 = __fadd_rn(__fadd_rn(__fmul_rn(ex,ex), __fmul_rn(ey,ey)),
                                         __fmul_rn(ez,ez));
                    nd = fminf(nd, e2);
                }
                distl[g] = nd;
                bv = nd; bidx = __float_as_int(P.w);
            }
            int o1 = lane + 64;
            if (o1 < len) {
                int g = st + o1;
                float4 P = sp[g];
                float D = distl[g];
                float dx = __fsub_rn(P.x, q1x), dy = __fsub_rn(P.y, q1y), dz = __fsub_rn(P.z, q1z);
                float d2 = __fadd_rn(__fadd_rn(__fmul_rn(dx,dx), __fmul_rn(dy,dy)),
                                     __fmul_rn(dz,dz));
                float nd = fminf(D, d2);
                if (two) {
                    float ex = __fsub_rn(P.x, q2x), ey = __fsub_rn(P.y, q2y), ez = __fsub_rn(P.z, q2z);
                    float e2 = __fadd_rn(__fadd_rn(__fmul_rn(ex,ex), __fmul_rn(ey,ey)),
                                         __fmul_rn(ez,ez));
                    nd = fminf(nd, e2);
                }
                distl[g] = nd;
                int oi = __float_as_int(P.w);
                bool b = (nd > bv) || (nd == bv && oi < bidx);
                bv = b ? nd : bv; bidx = b ? oi : bidx;
            }
            DPP_SWEEP(DPP_PAIR);                   // lane63 = chunk lexicographic max
            if (lane == 63)
                atomicMax(&key[c],
                          ((unsigned long long)__float_as_uint(bv) << 32) |
                          (unsigned long long)(~(unsigned)bidx));
        }
        __syncthreads();

        // ---- phase 3: top-2 over 512 cell keys
        kreg = key[t];
        unsigned long long k1 = kreg, k2 = 0ull;
        DPP_SWEEP(DPP_TOP2);
        if (lane == 63) { skw1[wave] = k1; skw2[wave] = k2; }
        if (t == 0) wlc = 0;
        __syncthreads();

        unsigned long long A1 = skw1[0], A2 = skw2[0];
#define MRG(w) { unsigned long long B1 = skw1[w], B2 = skw2[w]; \
        unsigned long long n1 = A1 > B1 ? A1 : B1; \
        unsigned long long lo = A1 > B1 ? B1 : A1; \
        unsigned long long m2 = A2 > B2 ? A2 : B2; \
        A2 = lo > m2 ? lo : m2; A1 = n1; }
        MRG(1) MRG(2) MRG(3) MRG(4) MRG(5) MRG(6) MRG(7)
#undef MRG

        int s1 = (int)(~(unsigned)(A1 & 0xFFFFFFFFull));
        int s2 = (int)(~(unsigned)(A2 & 0xFFFFFFFFull));
        if (t == 0) sel[it] = s1;

        int us1 = __builtin_amdgcn_readfirstlane(s1);
        int us2 = __builtin_amdgcn_readfirstlane(s2);
        float nq1x = p[us1*3+0], nq1y = p[us1*3+1], nq1z = p[us1*3+2];
        float bx2 = p[us2*3+0], by2 = p[us2*3+1], bz2 = p[us2*3+2];

        first = false;
        two = false;
        int nsel = 1;
        if (A2 != 0ull && it + 1 < M_CTR) {
            // exact: if d2(b, s1) >= dist(b), b's key is unchanged by s1's update
            float dx = __fsub_rn(bx2, nq1x), dy = __fsub_rn(by2, nq1y), dz = __fsub_rn(bz2, nq1z);
            float d2b = __fadd_rn(__fadd_rn(__fmul_rn(dx,dx), __fmul_rn(dy,dy)),
                                  __fmul_rn(dz,dz));
            float db = __uint_as_float((unsigned)(A2 >> 32));
            if (d2b >= db) {
                two = true;
                q2x = bx2; q2y = by2; q2z = bz2;
                if (t == 0) sel[it + 1] = s2;
                nsel = 2;
            }
        }
        q1x = nq1x; q1y = nq1y; q1z = nq1z;
        it += nsel;
    }
}

// ---------------- prep: pp2, gather n_p/n_n, write n_o ----------------
__global__ void prep_kernel(const float* __restrict__ p, const float* __restrict__ nrm,
                            const int* __restrict__ sel, float* __restrict__ pp2,
                            float* __restrict__ out)
{
    int i = blockIdx.x * blockDim.x + threadIdx.x;
    if (i < N_PTS) {
        float x = p[i*3], y = p[i*3+1], z = p[i*3+2];
        pp2[i] = __fadd_rn(__fadd_rn(__fmul_rn(x,x), __fmul_rn(y,y)), __fmul_rn(z,z));
    }
    if (i < M_CTR) {
        int j = sel[i];
        out[i*3+0] = p[j*3+0]; out[i*3+1] = p[j*3+1]; out[i*3+2] = p[j*3+2];
        out[12288 + i*3+0] = nrm[j*3+0];
        out[12288 + i*3+1] = nrm[j*3+1];
        out[12288 + i*3+2] = nrm[j*3+2];
    }
    if (i == 0) out[548864] = (float)M_CTR;   // n_o
}

// ---------------- kNN: one wave per center, per-lane sorted top-16 ----------------
__global__ __launch_bounds__(256) void knn_kernel(const float* __restrict__ p,
                                                  const float* __restrict__ pp2,
                                                  const float* __restrict__ np /* n_p */,
                                                  int* __restrict__ knn)
{
    const int lane = threadIdx.x & 63;
    const int wave = threadIdx.x >> 6;
    const int c = blockIdx.x * 4 + wave;

    float cx = np[c*3], cy = np[c*3+1], cz = np[c*3+2];
    float c2 = __fadd_rn(__fadd_rn(__fmul_rn(cx,cx), __fmul_rn(cy,cy)), __fmul_rn(cz,cz));

    float hd[16]; int hi[16];
#pragma unroll
    for (int k = 0; k < 16; ++k) { hd[k] = 1e30f; hi[k] = 0x7fffffff; }

    for (int t = 0; t < N_PTS/64; ++t) {
        int j = t*64 + lane;
        float px = p[j*3+0], py = p[j*3+1], pz = p[j*3+2];
        float dot = __fadd_rn(__fadd_rn(__fmul_rn(cx,px), __fmul_rn(cy,py)),
                              __fmul_rn(cz,pz));
        float d2  = __fsub_rn(__fadd_rn(c2, pp2[j]), __fmul_rn(2.0f, dot));
        if (d2 < hd[15]) {
#pragma unroll
            for (int k = 15; k >= 1; --k) {
                bool up   = d2 < hd[k-1];
                bool here = d2 < hd[k];
                hd[k] = up ? hd[k-1] : (here ? d2 : hd[k]);
                hi[k] = up ? hi[k-1] : (here ? j  : hi[k]);
            }
            if (d2 < hd[0]) { hd[0] = d2; hi[0] = j; }
        }
    }

    for (int r = 0; r < 16; ++r) {
        float wv = hd[0]; int wi = hi[0];
#pragma unroll
        for (int m = 1; m < 64; m <<= 1) {
            float ov = __shfl_xor(wv, m);
            int   oi = __shfl_xor(wi, m);
            bool b = (ov < wv) || (ov == wv && oi < wi);
            wv = b ? ov : wv; wi = b ? oi : wi;
        }
        if (hi[0] == wi) {
            knn[c*16 + r] = wi;
#pragma unroll
            for (int k = 0; k < 15; ++k) { hd[k] = hd[k+1]; hi[k] = hi[k+1]; }
            hd[15] = 1e30f; hi[15] = 0x7fffffff;
        }
    }
}

// ---------------- pass A: feat build + GEMM + stats + ymax/ymin ----------------
__global__ __launch_bounds__(128) void passA_kernel(const float* __restrict__ p,
                                                    const float* __restrict__ xf,
                                                    const float* __restrict__ W,
                                                    const int* __restrict__ knn,
                                                    const float* __restrict__ out /* n_p */,
                                                    float* __restrict__ ymax,
                                                    float* __restrict__ ymin,
                                                    float* __restrict__ partials)
{
    __shared__ float Wt[CFEAT][COUT];
    __shared__ float ft[CPB][NS][CFEAT];
    __shared__ float bsum[CPB][COUT], bssq[CPB][COUT];

    const int t = threadIdx.x;
    const int mbase = blockIdx.x * CPB;

    for (int c = 0; c < CFEAT; ++c) Wt[c][t] = W[t*CFEAT + c];

    {
        int r = t >> 1, half = t & 1;
        int ci = r >> 4, s = r & 15;
        int m = mbase + ci;
        int nb = knn[m*NS + s];
        if (half == 0) {
            ft[ci][s][0] = __fsub_rn(p[nb*3+0], out[m*3+0]);
            ft[ci][s][1] = __fsub_rn(p[nb*3+1], out[m*3+1]);
            ft[ci][s][2] = __fsub_rn(p[nb*3+2], out[m*3+2]);
        }
        for (int c = half*32; c < half*32 + 32; ++c)
            ft[ci][s][3+c] = xf[nb*CIN + c];
    }
    __syncthreads();

    const int ci = t >> 5, l = t & 31;
    float acc[NS][4];
#pragma unroll
    for (int s = 0; s < NS; ++s) { acc[s][0]=0.f; acc[s][1]=0.f; acc[s][2]=0.f; acc[s][3]=0.f; }

    for (int c = 0; c < CFEAT; ++c) {
        float w0 = Wt[c][l], w1 = Wt[c][l+32], w2 = Wt[c][l+64], w3 = Wt[c][l+96];
#pragma unroll
        for (int s = 0; s < NS; ++s) {
            float f = ft[ci][s][c];
            acc[s][0] = fmaf(f, w0, acc[s][0]);
            acc[s][1] = fmaf(f, w1, acc[s][1]);
            acc[s][2] = fmaf(f, w2, acc[s][2]);
            acc[s][3] = fmaf(f, w3, acc[s][3]);
        }
    }

    const int m = mbase + ci;
#pragma unroll
    for (int j = 0; j < 4; ++j) {
        int o = l + 32*j;
        float s = 0.f, q = 0.f, mx = -1e30f, mn = 1e30f;
#pragma unroll
        for (int sidx = 0; sidx < NS; ++sidx) {
            float v = acc[sidx][j];
            s += v; q = fmaf(v, v, q);
            mx = fmaxf(mx, v); mn = fminf(mn, v);
        }
        bsum[ci][o] = s;
        bssq[ci][o] = q;
        ymax[m*COUT + o] = mx;
        ymin[m*COUT + o] = mn;
    }
    __syncthreads();
    if (t < COUT) {
        float s = bsum[0][t] + bsum[1][t] + bsum[2][t] + bsum[3][t];
        float q = bssq[0][t] + bssq[1][t] + bssq[2][t] + bssq[3][t];
        partials[t*1024          + blockIdx.x] = s;
        partials[(COUT + t)*1024 + blockIdx.x] = q;
    }
}

// ---------------- BN stats reduce -> scale/shift ----------------
__global__ __launch_bounds__(256) void bnstat_kernel(const float* __restrict__ partials,
                                                     const float* __restrict__ gamma,
                                                     const float* __restrict__ beta,
                                                     float* __restrict__ scaleshift)
{
    __shared__ float red[256];
    int t = threadIdx.x;
    const float4* v4 = (const float4*)(partials + t*1024);
    float s = 0.f;
    for (int i = 0; i < 256; ++i) {
        float4 v = v4[i];
        s += v.x; s += v.y; s += v.z; s += v.w;
    }
    red[t] = s;
    __syncthreads();
    if (t < COUT) {
        const float inv = 1.0f / 65536.0f;
        float mean = red[t] * inv;
        float var  = red[COUT + t] * inv - mean*mean;
        float rstd = rsqrtf(var + 1e-5f);
        float g = gamma[t] * rstd;
        scaleshift[t]        = g;
        scaleshift[COUT + t] = beta[t] - mean * g;
    }
}

// ---------------- final: BN apply + ReLU on the pooled extreme ----------------
__global__ void final_kernel(float* __restrict__ y,
                             const float* __restrict__ ymin,
                             const float* __restrict__ scaleshift)
{
    int i = blockIdx.x * blockDim.x + threadIdx.x;
    if (i >= M_CTR * COUT) return;
    int o = i & (COUT - 1);
    float a = scaleshift[o], b = scaleshift[COUT + o];
    float v = (a >= 0.f) ? y[i] : ymin[i];
    float z = fmaf(a, v, b);
    y[i] = fmaxf(z, 0.f);
}

extern "C" void kernel_launch(void* const* d_in, const int* in_sizes, int n_in,
                              void* d_out, int out_size, void* d_ws, size_t ws_size,
                              hipStream_t stream)
{
    const float* p     = (const float*)d_in[0];
    const float* nrm   = (const float*)d_in[1];
    const float* xf    = (const float*)d_in[2];
    // d_in[3] = o (unused: single batch, static sizes)
    const float* W     = (const float*)d_in[4];
    const float* gamma = (const float*)d_in[5];
    const float* beta  = (const float*)d_in[6];

    float* out = (float*)d_out;
    char* ws = (char*)d_ws;
    int*   sel        = (int*)(ws + 0);            // 16 KB
    float* pp2        = (float*)(ws + 16384);      // 64 KB
    int*   knn        = (int*)(ws + 81920);        // 256 KB (overlaid by sp during FPS)
    float* ymin       = (float*)(ws + 344064);     // 2 MB  (head overlaid by FPS scratch)
    float* partials   = (float*)(ws + 2441216);    // 1 MB
    float* scaleshift = (float*)(ws + 3489792);    // 1 KB

    // FPS scratch overlays (consumed before their hosts are written):
    float4*   sp        = (float4*)(ws + 81920);            // 256 KB in knn region
    char*     yb        = ws + 344064;                      // ymin region
    int*      c_of      = (int*)(yb + 65536);               // 64 KB
    int*      cellcnt   = (int*)(yb + 131072);              // 2 KB
    int*      cellfill  = (int*)(yb + 133120);              // 2 KB
    int*      cellstart = (int*)(yb + 135168);              // 2 KB
    unsigned* bbmin_u   = (unsigned*)(yb + 137216);         // 6 KB
    unsigned* bbmax_u   = (unsigned*)(yb + 143360);         // 6 KB
    float*    gbb       = (float*)(yb + 149504);            // 24 B
    int*      cmeta_g   = (int*)(yb + 149536);              // 2 KB

    float* ymax = out + 24576;  // y region of d_out

    init_kernel   <<<8,  256, 0, stream>>>(bbmin_u, bbmax_u, cellcnt, cellfill);
    bbox_kernel   <<<1,  256, 0, stream>>>(p, gbb);
    assign_kernel <<<64, 256, 0, stream>>>(p, gbb, c_of, cellcnt);
    prefix_kernel <<<1,  512, 0, stream>>>(cellcnt, cellstart, cmeta_g);
    scatter_kernel<<<64, 256, 0, stream>>>(p, c_of, cellstart, cellfill, sp, bbmin_u, bbmax_u);
    fps_kernel    <<<1,  512, 0, stream>>>(p, sp, cmeta_g, bbmin_u, bbmax_u, sel);
    prep_kernel   <<<64, 256, 0, stream>>>(p, nrm, sel, pp2, out);
    knn_kernel    <<<1024, 256, 0, stream>>>(p, pp2, out, knn);
    passA_kernel  <<<M_CTR/CPB, 128, 0, stream>>>(p, xf, W, knn, out, ymax, ymin, partials);
    bnstat_kernel <<<1, 256, 0, stream>>>(partials, gamma, beta, scaleshift);
    final_kernel  <<<2048, 256, 0, stream>>>(ymax, ymin, scaleshift);
}